// Round 3
// baseline (335.563 us; speedup 1.0000x reference)
//
#include <hip/hip_runtime.h>

// Problem constants
#define B_ 512
#define L_ 256
#define D_ 1024
#define H_ 16
#define DK_ 64
#define DV_ 64
// TEMP = sqrt(1024) = 32 exactly (folded into Aq in k_aq)

typedef float f32x4 __attribute__((ext_vector_type(4)));
typedef float f32x2 __attribute__((ext_vector_type(2)));
typedef __bf16 bf16x8 __attribute__((ext_vector_type(8)));
typedef __bf16 bf16x2 __attribute__((ext_vector_type(2)));

#define MFMA16(a, b, c) __builtin_amdgcn_mfma_f32_16x16x32_bf16((a), (b), (c), 0, 0, 0)

__device__ inline bf16x8 cvt8(f32x4 a, f32x4 b) {
  bf16x8 r;
  r[0] = (__bf16)a[0]; r[1] = (__bf16)a[1]; r[2] = (__bf16)a[2]; r[3] = (__bf16)a[3];
  r[4] = (__bf16)b[0]; r[5] = (__bf16)b[1]; r[6] = (__bf16)b[2]; r[7] = (__bf16)b[3];
  return r;
}

// ---------------------------------------------------------------------------
// K1: hq[b, h*DK+kk] = sum_d q[b,d] * Wq[h*DK+kk, d]   (Wq viewed [1024][1024])
// ---------------------------------------------------------------------------
__global__ __launch_bounds__(256) void k_hq(const float* __restrict__ q,
                                            const float* __restrict__ Wq,
                                            __bf16* __restrict__ hq) {
  int tid = threadIdx.x, lane = tid & 63, wid = tid >> 6;
  int r16 = lane & 15, g = lane >> 4;
  int n0 = (blockIdx.x * 4 + wid) * 16;
  int m0 = blockIdx.y * 16;
  const float* arow = q  + (size_t)(m0 + r16) * D_;
  const float* brow = Wq + (size_t)(n0 + r16) * D_;
  f32x4 acc = {0.f, 0.f, 0.f, 0.f};
  for (int ks = 0; ks < D_ / 32; ++ks) {
    int k0 = ks * 32 + g * 8;
    f32x4 a0 = *(const f32x4*)(arow + k0);
    f32x4 a1 = *(const f32x4*)(arow + k0 + 4);
    f32x4 b0 = *(const f32x4*)(brow + k0);
    f32x4 b1 = *(const f32x4*)(brow + k0 + 4);
    acc = MFMA16(cvt8(a0, a1), cvt8(b0, b1), acc);
  }
#pragma unroll
  for (int r = 0; r < 4; ++r) {
    int m = m0 + g * 4 + r;
    hq[(size_t)m * (H_ * DK_) + n0 + r16] = (__bf16)acc[r];
  }
}

// ---------------------------------------------------------------------------
// K2: Aq[b, h, d] = (1/32) * sum_kk hq[b, h*64+kk] * Wk[h, kk, d]
// (temperature folded here; 1/32 is a power of 2 -> exact in bf16)
// ---------------------------------------------------------------------------
__global__ __launch_bounds__(256) void k_aq(const __bf16* __restrict__ hq,
                                            const float* __restrict__ Wk,
                                            __bf16* __restrict__ Aq) {
  int tid = threadIdx.x, lane = tid & 63, wid = tid >> 6;
  int r16 = lane & 15, g = lane >> 4;
  int h = blockIdx.z;
  int n0 = (blockIdx.x * 4 + wid) * 16;
  int m0 = blockIdx.y * 16;
  const __bf16* arow = hq + (size_t)(m0 + r16) * (H_ * DK_) + h * DK_;
  const float* bcol = Wk + (size_t)h * DK_ * D_ + n0 + r16;  // + k*D_
  f32x4 acc = {0.f, 0.f, 0.f, 0.f};
#pragma unroll
  for (int ks = 0; ks < 2; ++ks) {
    int k0 = ks * 32 + g * 8;
    bf16x8 a = *(const bf16x8*)(arow + k0);
    f32x4 c0, c1;
#pragma unroll
    for (int j = 0; j < 4; ++j) c0[j] = bcol[(size_t)(k0 + j) * D_];
#pragma unroll
    for (int j = 0; j < 4; ++j) c1[j] = bcol[(size_t)(k0 + 4 + j) * D_];
    acc = MFMA16(a, cvt8(c0, c1), acc);
  }
#pragma unroll
  for (int r = 0; r < 4; ++r) {
    int m = m0 + g * 4 + r;
    Aq[(size_t)m * (H_ * D_) + (size_t)h * D_ + n0 + r16] = (__bf16)(acc[r] * 0.03125f);
  }
}

// ---------------------------------------------------------------------------
// K3: fused attention per b. block 512 (8 waves), grid 512.
//   Phase A: scores[16,256] = Aq_b[16,1024] * k_b^T   (MFMA, coalesced k)
//   softmax over l per head
//   Phase B: cv[16,1024] = w[16,256] * v_b[256,1024]  (VALU, coalesced v)
// LDS: 16.6KB scores + 20KB wT = 36.6KB -> 4 blocks/CU.
// ---------------------------------------------------------------------------
#define WPAD 20
__global__ __launch_bounds__(512) void k_attn2(const float* __restrict__ kg,
                                               const float* __restrict__ vg,
                                               const __bf16* __restrict__ Aq,
                                               __bf16* __restrict__ cv) {
  __shared__ float s_lds[H_][L_ + 4];   // raw scores [h][l]
  __shared__ float wT[L_][WPAD];        // normalized weights, transposed [l][h]

  int b = blockIdx.x;
  int tid = threadIdx.x, lane = tid & 63, wv = tid >> 6;  // wv in 0..7
  int r16 = lane & 15, g = lane >> 4;
  const __bf16* AqB = Aq + (size_t)b * H_ * D_;
  const float*  kB  = kg + (size_t)b * L_ * D_;
  const float*  vB  = vg + (size_t)b * L_ * D_;

  // ---- Phase A: wave wv owns l in [wv*32, wv*32+32) = 2 ntiles.
  f32x4 accA[2] = {{0.f,0.f,0.f,0.f}, {0.f,0.f,0.f,0.f}};
  const float* kR0 = kB + (size_t)(wv * 32 + r16) * D_;
  const float* kR1 = kB + (size_t)(wv * 32 + 16 + r16) * D_;
#pragma unroll 4
  for (int ks = 0; ks < D_ / 32; ++ks) {
    int k0 = ks * 32 + g * 8;
    bf16x8 a = *(const bf16x8*)(AqB + (size_t)r16 * D_ + k0);
    accA[0] = MFMA16(a, cvt8(*(const f32x4*)(kR0 + k0), *(const f32x4*)(kR0 + k0 + 4)), accA[0]);
    accA[1] = MFMA16(a, cvt8(*(const f32x4*)(kR1 + k0), *(const f32x4*)(kR1 + k0 + 4)), accA[1]);
  }
#pragma unroll
  for (int nt = 0; nt < 2; ++nt)
#pragma unroll
    for (int r = 0; r < 4; ++r)
      s_lds[g * 4 + r][wv * 32 + nt * 16 + r16] = accA[nt][r];
  __syncthreads();

  // ---- Softmax: wave wv handles head rows wv*2, wv*2+1; write wT[l][h].
#pragma unroll
  for (int rr = 0; rr < 2; ++rr) {
    int row = wv * 2 + rr;
    float x0 = s_lds[row][lane];
    float x1 = s_lds[row][lane + 64];
    float x2 = s_lds[row][lane + 128];
    float x3 = s_lds[row][lane + 192];
    float m = fmaxf(fmaxf(x0, x1), fmaxf(x2, x3));
#pragma unroll
    for (int off = 32; off; off >>= 1) m = fmaxf(m, __shfl_xor(m, off));
    float e0 = __expf(x0 - m), e1 = __expf(x1 - m);
    float e2 = __expf(x2 - m), e3 = __expf(x3 - m);
    float s = e0 + e1 + e2 + e3;
#pragma unroll
    for (int off = 32; off; off >>= 1) s += __shfl_xor(s, off);
    float inv = 1.0f / s;
    wT[lane]      [row] = e0 * inv;
    wT[lane + 64] [row] = e1 * inv;
    wT[lane + 128][row] = e2 * inv;
    wT[lane + 192][row] = e3 * inv;
  }
  __syncthreads();

  // ---- Phase B: thread owns 2 d-cols; stream v coalesced, w broadcast.
  int c0 = tid * 2;
  const float* vC = vB + c0;
  f32x2 acc[16];
#pragma unroll
  for (int h = 0; h < 16; ++h) acc[h] = (f32x2){0.f, 0.f};

#pragma unroll 2
  for (int l = 0; l < L_; ++l) {
    f32x2 v2 = *(const f32x2*)(vC + (size_t)l * D_);
    f32x4 w0 = *(const f32x4*)(&wT[l][0]);   // broadcast reads
    f32x4 w1 = *(const f32x4*)(&wT[l][4]);
    f32x4 w2 = *(const f32x4*)(&wT[l][8]);
    f32x4 w3 = *(const f32x4*)(&wT[l][12]);
#pragma unroll
    for (int j = 0; j < 4; ++j) {
      acc[j]      += w0[j] * v2;
      acc[4 + j]  += w1[j] * v2;
      acc[8 + j]  += w2[j] * v2;
      acc[12 + j] += w3[j] * v2;
    }
  }
#pragma unroll
  for (int h = 0; h < 16; ++h) {
    bf16x2 o;
    o[0] = (__bf16)acc[h][0];
    o[1] = (__bf16)acc[h][1];
    *(bf16x2*)(cv + ((size_t)b * H_ + h) * D_ + c0) = o;
  }
}

// ---------------------------------------------------------------------------
// K4: ctx[b, h*64+vv] = sum_d cv[b,h,d] * Wv[h,vv,d]
// ---------------------------------------------------------------------------
__global__ __launch_bounds__(256) void k_ctx(const __bf16* __restrict__ cv,
                                             const float* __restrict__ Wv,
                                             __bf16* __restrict__ ctx) {
  int tid = threadIdx.x, lane = tid & 63, wid = tid >> 6;
  int r16 = lane & 15, g = lane >> 4;
  int h = blockIdx.z, m0 = blockIdx.y * 16, n0 = wid * 16;
  const __bf16* arow = cv + (size_t)(m0 + r16) * (H_ * D_) + (size_t)h * D_;
  const float* brow = Wv + (size_t)h * DV_ * D_ + (size_t)(n0 + r16) * D_;
  f32x4 acc = {0.f, 0.f, 0.f, 0.f};
  for (int ks = 0; ks < D_ / 32; ++ks) {
    int k0 = ks * 32 + g * 8;
    bf16x8 a = *(const bf16x8*)(arow + k0);
    f32x4 b0 = *(const f32x4*)(brow + k0);
    f32x4 b1 = *(const f32x4*)(brow + k0 + 4);
    acc = MFMA16(a, cvt8(b0, b1), acc);
  }
#pragma unroll
  for (int r = 0; r < 4; ++r) {
    int m = m0 + g * 4 + r;
    ctx[(size_t)m * (H_ * DV_) + h * DV_ + n0 + r16] = (__bf16)acc[r];
  }
}

// ---------------------------------------------------------------------------
// K5: outp[b,d] = sum_j ctx[b,j] * Wp[d,j] + q[b,d]
// ---------------------------------------------------------------------------
__global__ __launch_bounds__(256) void k_out(const __bf16* __restrict__ ctx,
                                             const float* __restrict__ Wp,
                                             const float* __restrict__ q,
                                             float* __restrict__ outp) {
  int tid = threadIdx.x, lane = tid & 63, wid = tid >> 6;
  int r16 = lane & 15, g = lane >> 4;
  int n0 = (blockIdx.x * 4 + wid) * 16;
  int m0 = blockIdx.y * 16;
  const __bf16* arow = ctx + (size_t)(m0 + r16) * D_;
  const float* brow = Wp + (size_t)(n0 + r16) * D_;
  f32x4 acc = {0.f, 0.f, 0.f, 0.f};
  for (int ks = 0; ks < D_ / 32; ++ks) {
    int k0 = ks * 32 + g * 8;
    bf16x8 a = *(const bf16x8*)(arow + k0);
    f32x4 b0 = *(const f32x4*)(brow + k0);
    f32x4 b1 = *(const f32x4*)(brow + k0 + 4);
    acc = MFMA16(a, cvt8(b0, b1), acc);
  }
#pragma unroll
  for (int r = 0; r < 4; ++r) {
    int m = m0 + g * 4 + r;
    outp[(size_t)m * D_ + n0 + r16] = acc[r] + q[(size_t)m * D_ + n0 + r16];
  }
}

// ---------------------------------------------------------------------------
// K6: LayerNorm, unbiased std (D-1), eps=1 added to STD.
// ---------------------------------------------------------------------------
__global__ __launch_bounds__(256) void k_ln(const float* __restrict__ xin,
                                            const float* __restrict__ scale,
                                            const float* __restrict__ offs,
                                            float* __restrict__ out) {
  __shared__ float red[4];
  int b = blockIdx.x, tid = threadIdx.x;
  const float* row = xin + (size_t)b * D_;
  f32x4 x = *(const f32x4*)(row + tid * 4);
  float s = x[0] + x[1] + x[2] + x[3];
#pragma unroll
  for (int off = 32; off; off >>= 1) s += __shfl_xor(s, off);
  if ((tid & 63) == 0) red[tid >> 6] = s;
  __syncthreads();
  float mean = (red[0] + red[1] + red[2] + red[3]) * (1.0f / D_);
  __syncthreads();  // before reusing red
  float vs = 0.f;
#pragma unroll
  for (int j = 0; j < 4; ++j) { float d = x[j] - mean; vs += d * d; }
#pragma unroll
  for (int off = 32; off; off >>= 1) vs += __shfl_xor(vs, off);
  if ((tid & 63) == 0) red[tid >> 6] = vs;
  __syncthreads();
  float var = (red[0] + red[1] + red[2] + red[3]) * (1.0f / (D_ - 1));
  float inv = 1.0f / (sqrtf(var) + 1.0f);
  f32x4 sc = *(const f32x4*)(scale + tid * 4);
  f32x4 of = *(const f32x4*)(offs + tid * 4);
  f32x4 o;
#pragma unroll
  for (int j = 0; j < 4; ++j) o[j] = sc[j] * (x[j] - mean) * inv + of[j];
  *(f32x4*)(out + (size_t)b * D_ + tid * 4) = o;
}

// ---------------------------------------------------------------------------
extern "C" void kernel_launch(void* const* d_in, const int* in_sizes, int n_in,
                              void* d_out, int out_size, void* d_ws, size_t ws_size,
                              hipStream_t stream) {
  const float* q     = (const float*)d_in[0];
  const float* k     = (const float*)d_in[1];
  const float* v     = (const float*)d_in[2];
  const float* Wq    = (const float*)d_in[3];
  const float* Wk    = (const float*)d_in[4];
  const float* Wv    = (const float*)d_in[5];
  const float* Wp    = (const float*)d_in[6];
  const float* scale = (const float*)d_in[7];
  const float* offs  = (const float*)d_in[8];
  float* out = (float*)d_out;

  // Workspace layout:
  char* ws = (char*)d_ws;
  __bf16* hq   = (__bf16*)(ws);                          // 1 MB
  __bf16* Aq   = (__bf16*)(ws + (size_t)1  * (1 << 20)); // 16 MB
  __bf16* cv   = (__bf16*)(ws + (size_t)17 * (1 << 20)); // 16 MB
  __bf16* ctx  = (__bf16*)(ws + (size_t)33 * (1 << 20)); // 1 MB
  float*  outp = (float*) (ws + (size_t)34 * (1 << 20)); // 2 MB

  k_hq   <<<dim3(16, 32),     256, 0, stream>>>(q, Wq, hq);
  k_aq   <<<dim3(16, 32, 16), 256, 0, stream>>>(hq, Wk, Aq);
  k_attn2<<<dim3(512),        512, 0, stream>>>(k, v, Aq, cv);
  k_ctx  <<<dim3(1, 32, 16),  256, 0, stream>>>(cv, Wv, ctx);
  k_out  <<<dim3(16, 32),     256, 0, stream>>>(ctx, Wp, q, outp);
  k_ln   <<<dim3(512),        256, 0, stream>>>(outp, scale, offs, out);
}